// Round 7
// baseline (89.647 us; speedup 1.0000x reference)
//
#include <hip/hip_runtime.h>

#define Q 4096
#define L 8192
#define NWB 1024               // K2: ctx weighted-sum blocks
#define RWB (L / NWB)          // 8 rows per wsum block
#define NKB 1024               // K2: Kw_left blocks (4 waves, 1 row/wave)
#define NRB 64                 // K2b: reduce blocks

// ---------------------------------------------------------------------------
// K1: score[l] = dot(ctx[l], q). One block per row (proven ~6.4 TB/s in R1).
// ---------------------------------------------------------------------------
__global__ __launch_bounds__(256) void score_kernel(
    const float* __restrict__ ctx, const float* __restrict__ q,
    float* __restrict__ score)
{
    const int l = blockIdx.x;
    const float4* __restrict__ row = (const float4*)(ctx + (size_t)l * Q);
    const float4* __restrict__ qv  = (const float4*)q;

    float acc = 0.f;
    #pragma unroll
    for (int i = threadIdx.x; i < Q / 4; i += 256) {
        float4 a = row[i];
        float4 b = qv[i];
        acc = fmaf(a.x, b.x, acc);
        acc = fmaf(a.y, b.y, acc);
        acc = fmaf(a.z, b.z, acc);
        acc = fmaf(a.w, b.w, acc);
    }
    #pragma unroll
    for (int off = 32; off > 0; off >>= 1) acc += __shfl_down(acc, off, 64);

    __shared__ float red[4];
    const int lane = threadIdx.x & 63;
    const int wid  = threadIdx.x >> 6;
    if (lane == 0) red[wid] = acc;
    __syncthreads();
    if (threadIdx.x == 0)
        score[l] = red[0] + red[1] + red[2] + red[3];
}

// ---------------------------------------------------------------------------
// K2, blocks [0,NWB): redundant softmax stats (score is 32KB, L2-hot), then
//   barrier-free weighted sum of this block's 8 ctx rows (ctx is L3-hot from
//   K1).  Writes FINAL-normalized partial row.
// K2, blocks [NWB,NWB+NKB): out1[i] = Kw[i,0:Q].q (HBM stream, overlaps the
//   L3-bound ctx half).  One wave per row.
// ---------------------------------------------------------------------------
__global__ __launch_bounds__(256) void k2_kernel(
    const float* __restrict__ qvec, const float* __restrict__ ctx,
    const float* __restrict__ Kw, const float* __restrict__ score,
    float* __restrict__ partial, float* __restrict__ out1)
{
    const int tid  = threadIdx.x;
    const int lane = tid & 63;
    const int wid  = tid >> 6;

    if (blockIdx.x < NWB) {
        // ---- softmax stats: per-thread online (m,z) over 32 scores ----
        __shared__ float redm[4], redz[4];
        float mt = -3.4e38f, zt = 0.f;
        for (int i = tid; i < L; i += 256) {
            const float s = score[i];
            if (s > mt) { zt *= __expf(mt - s); mt = s; }
            zt += __expf(s - mt);
        }
        #pragma unroll
        for (int off = 32; off > 0; off >>= 1) {
            const float om = __shfl_down(mt, off, 64);
            const float oz = __shfl_down(zt, off, 64);
            if (om > mt) { zt = zt * __expf(mt - om) + oz; mt = om; }
            else         { zt += oz * __expf(om - mt); }
        }
        if (lane == 0) { redm[wid] = mt; redz[wid] = zt; }
        __syncthreads();
        float M = redm[0], Zc = redz[0];
        #pragma unroll
        for (int wv = 1; wv < 4; ++wv) {
            const float om = redm[wv], oz = redz[wv];
            if (om > M) { Zc = Zc * __expf(M - om) + oz; M = om; }
            else        { Zc += oz * __expf(om - M); }
        }
        const float invZ = 1.f / Zc;

        // ---- final weights for this block's rows ----
        const int r0 = blockIdx.x * RWB;
        float w[RWB];
        #pragma unroll
        for (int r = 0; r < RWB; ++r)
            w[r] = __expf(score[r0 + r] - M) * invZ;

        // ---- barrier-free weighted sum: 32 independent 16B loads ----
        const float4* __restrict__ cb = (const float4*)ctx;
        float4 acc[4];
        #pragma unroll
        for (int k = 0; k < 4; ++k) acc[k] = make_float4(0.f, 0.f, 0.f, 0.f);
        #pragma unroll
        for (int r = 0; r < RWB; ++r) {
            const float wr = w[r];
            #pragma unroll
            for (int k = 0; k < 4; ++k) {
                float4 v = cb[(size_t)(r0 + r) * (Q / 4) + tid + k * 256];
                acc[k].x = fmaf(wr, v.x, acc[k].x);
                acc[k].y = fmaf(wr, v.y, acc[k].y);
                acc[k].z = fmaf(wr, v.z, acc[k].z);
                acc[k].w = fmaf(wr, v.w, acc[k].w);
            }
        }
        float4* __restrict__ pb = (float4*)(partial + (size_t)blockIdx.x * Q);
        #pragma unroll
        for (int k = 0; k < 4; ++k) pb[tid + k * 256] = acc[k];
    } else {
        // ---- out1[i] = Kw[i, 0:Q] . q : one wave per row ----
        const int i = (blockIdx.x - NWB) * 4 + wid;      // 0..4095
        const float4* __restrict__ row = (const float4*)(Kw + (size_t)i * (2 * Q));
        const float4* __restrict__ qg  = (const float4*)qvec;
        float a0 = 0.f, a1 = 0.f, a2 = 0.f, a3 = 0.f;
        #pragma unroll
        for (int c = 0; c < 16; c += 4) {
            float4 x0 = row[(c + 0) * 64 + lane], y0 = qg[(c + 0) * 64 + lane];
            float4 x1 = row[(c + 1) * 64 + lane], y1 = qg[(c + 1) * 64 + lane];
            float4 x2 = row[(c + 2) * 64 + lane], y2 = qg[(c + 2) * 64 + lane];
            float4 x3 = row[(c + 3) * 64 + lane], y3 = qg[(c + 3) * 64 + lane];
            a0 = fmaf(x0.x, y0.x, a0); a0 = fmaf(x0.y, y0.y, a0);
            a0 = fmaf(x0.z, y0.z, a0); a0 = fmaf(x0.w, y0.w, a0);
            a1 = fmaf(x1.x, y1.x, a1); a1 = fmaf(x1.y, y1.y, a1);
            a1 = fmaf(x1.z, y1.z, a1); a1 = fmaf(x1.w, y1.w, a1);
            a2 = fmaf(x2.x, y2.x, a2); a2 = fmaf(x2.y, y2.y, a2);
            a2 = fmaf(x2.z, y2.z, a2); a2 = fmaf(x2.w, y2.w, a2);
            a3 = fmaf(x3.x, y3.x, a3); a3 = fmaf(x3.y, y3.y, a3);
            a3 = fmaf(x3.z, y3.z, a3); a3 = fmaf(x3.w, y3.w, a3);
        }
        float dd = (a0 + a1) + (a2 + a3);
        #pragma unroll
        for (int off = 32; off > 0; off >>= 1) dd += __shfl_down(dd, off, 64);
        if (lane == 0) out1[i] = dd;
    }
}

// ---------------------------------------------------------------------------
// K2b: s_t[j] = sum_b partial[b][j]   (plain sum; weights already final)
//   64 blocks; block owns 16 float4 columns; 16 row-groups sweep NWB.
// ---------------------------------------------------------------------------
__global__ __launch_bounds__(256) void reduce_kernel(
    const float* __restrict__ partial, float* __restrict__ s_t)
{
    __shared__ float4 sacc[16][16];
    const int c  = threadIdx.x & 15;              // column within block
    const int g  = threadIdx.x >> 4;              // 0..15 row-group
    const int c4 = blockIdx.x * 16 + c;           // global float4 column
    const float4* __restrict__ p = (const float4*)partial;

    float4 acc = make_float4(0.f, 0.f, 0.f, 0.f);
    for (int b = g; b < NWB; b += 16) {
        float4 v = p[(size_t)b * (Q / 4) + c4];
        acc.x += v.x; acc.y += v.y; acc.z += v.z; acc.w += v.w;
    }
    sacc[g][c] = acc;
    __syncthreads();
    if (g == 0) {
        float4 t = sacc[0][c];
        #pragma unroll
        for (int gg = 1; gg < 16; ++gg) {
            float4 u = sacc[gg][c];
            t.x += u.x; t.y += u.y; t.z += u.z; t.w += u.w;
        }
        ((float4*)s_t)[c4] = t;
    }
}

// ---------------------------------------------------------------------------
// K3: out[i] = out1[i] + Kw[i, Q:2Q] . s_t   (one wave per row)
// ---------------------------------------------------------------------------
__global__ __launch_bounds__(256) void k3_kernel(
    const float* __restrict__ Kw, const float* __restrict__ s_t,
    const float* __restrict__ out1, float* __restrict__ out)
{
    const int lane = threadIdx.x & 63;
    const int wid  = threadIdx.x >> 6;
    const int i = blockIdx.x * 4 + wid;
    const float4* __restrict__ row = (const float4*)(Kw + (size_t)i * (2 * Q) + Q);
    const float4* __restrict__ sv  = (const float4*)s_t;
    float a = 0.f;
    #pragma unroll 4
    for (int it = 0; it < 16; ++it) {
        const int idx = it * 64 + lane;
        float4 x = row[idx], y = sv[idx];
        a = fmaf(x.x, y.x, a); a = fmaf(x.y, y.y, a);
        a = fmaf(x.z, y.z, a); a = fmaf(x.w, y.w, a);
    }
    #pragma unroll
    for (int off = 32; off > 0; off >>= 1) a += __shfl_down(a, off, 64);
    if (lane == 0) out[i] = out1[i] + a;
}

// ---------------------------------------------------------------------------
extern "C" void kernel_launch(void* const* d_in, const int* in_sizes, int n_in,
                              void* d_out, int out_size, void* d_ws, size_t ws_size,
                              hipStream_t stream)
{
    const float* query = (const float*)d_in[0];   // [Q]
    const float* ctx   = (const float*)d_in[1];   // [L, Q]
    const float* Kw    = (const float*)d_in[2];   // [Q, 2Q]
    float* out = (float*)d_out;                   // [Q]

    // workspace layout (floats)
    float* ws      = (float*)d_ws;
    float* score   = ws;                          // L     = 8192
    float* out1    = ws + L;                      // Q     = 4096
    float* s_t     = ws + L + Q;                  // Q     = 4096
    float* partial = ws + L + 2 * Q;              // NWB*Q = 16 MiB

    score_kernel<<<L, 256, 0, stream>>>(ctx, query, score);
    k2_kernel<<<NWB + NKB, 256, 0, stream>>>(query, ctx, Kw, score, partial, out1);
    reduce_kernel<<<NRB, 256, 0, stream>>>(partial, s_t);
    k3_kernel<<<Q / 4, 256, 0, stream>>>(Kw, s_t, out1, out);
}